// Round 8
// baseline (434.870 us; speedup 1.0000x reference)
//
#include <hip/hip_runtime.h>

#define T_STEPS 512
#define BATCH   2048
#define IN_F    12
#define E_F     15
#define H_F     20
#define G4      80
#define TC      16
#define NCHUNK  (T_STEPS / TC)

typedef float v2f __attribute__((ext_vector_type(2)));

// LDS float offsets (single wave per block -> no barriers anywhere). 12.2 KB
// total -> 8 blocks/CU (2 waves/SIMD) fit easily.
#define OFF_MD   0                    // [TC][12] md chunk                     = 192
#define OFF_HH   192                  // [TC][20] h history                    = 320
#define OFF_XG   512                  // [TC][88] swizzled x_gates             = 1408
#define OFF_WC   1920                 // 80x12 W_comb                          = 960
#define OFF_BC   2880                 // 80 fused bias                         = 80
#define OFF_WO   2960                 // [3][24] W_out + bias at +72           = 80
#define SMEM_FLOATS 3040              // 12160 bytes

// one-time raw staging aliased over [MD|HH|XG) (all first written later)
#define RAW_WEMB 0                    // 180
#define RAW_WIH  180                  // 1200
#define RAW_BEMB 1380                 // 15
#define RAW_BIH  1395                 // 80
#define RAW_BHH  1475                 // 80

// xg swizzle: unit u's 4 gate floats at tt*88 + u*4 + ((u>>3)<<2)  (16B aligned,
// spreads the 20 lanes' b128 reads across banks)
#define XGOFF(u) ((u) * 4 + (((u) >> 3) << 2))

__device__ __forceinline__ float fsig(float x) {
    float e = __builtin_amdgcn_exp2f(x * -1.442695040888963f);
    return __builtin_amdgcn_rcpf(1.0f + e);
}
__device__ __forceinline__ float ftanh(float x) {
    float e = __builtin_amdgcn_exp2f(x * -2.885390081777927f);
    return fmaf(2.0f, __builtin_amdgcn_rcpf(1.0f + e), -1.0f);
}
__device__ __forceinline__ v2f pkfma(v2f a, v2f b, v2f c) {
    return __builtin_elementwise_fma(a, b, c);
}

__global__ void __launch_bounds__(64, 2)
lstm_tracker_kernel(
    const float* __restrict__ md,
    const float* __restrict__ W_emb, const float* __restrict__ b_emb,
    const float* __restrict__ W_ih,  const float* __restrict__ b_ih,
    const float* __restrict__ W_hh,  const float* __restrict__ b_hh,
    const float* __restrict__ W_out, const float* __restrict__ b_out,
    float* __restrict__ out)
{
    __shared__ __align__(16) float smem[SMEM_FLOATS];
    const int lane = threadIdx.x;          // 0..63
    const int jj   = (lane < H_F) ? lane : 0;   // unit index, clamped
    const size_t b = blockIdx.x;           // this wave's sequence

    // ---- one-time: stage raw weights (single wave; DS in-order, no barriers) ----
    for (int i = lane; i < E_F * IN_F; i += 64) smem[RAW_WEMB + i] = W_emb[i];
    for (int i = lane; i < G4 * E_F;  i += 64) smem[RAW_WIH  + i] = W_ih[i];
    if (lane < E_F) smem[RAW_BEMB + lane] = b_emb[lane];
    for (int g = lane; g < G4; g += 64) smem[RAW_BIH + g] = b_ih[g];
    for (int g = lane; g < G4; g += 64) smem[RAW_BHH + g] = b_hh[g];
    for (int i = lane; i < 3 * H_F; i += 64) {
        int r = i / H_F, k = i - r * H_F;
        smem[OFF_WO + r * 24 + k] = W_out[i];
    }
    if (lane < 3) smem[OFF_WO + 72 + lane] = b_out[lane];

    // ---- one-time: W_comb = W_ih @ W_emb (80x12); b_comb = W_ih@b_emb + b_ih + b_hh ----
    for (int idx = lane; idx < G4 * IN_F; idx += 64) {
        int g = idx / IN_F, c = idx - g * IN_F;
        float s = 0.f;
        #pragma unroll
        for (int e = 0; e < E_F; ++e)
            s += smem[RAW_WIH + g * E_F + e] * smem[RAW_WEMB + e * IN_F + c];
        smem[OFF_WC + idx] = s;
    }
    for (int g = lane; g < G4; g += 64) {
        float s = smem[RAW_BIH + g] + smem[RAW_BHH + g];
        #pragma unroll
        for (int e = 0; e < E_F; ++e)
            s += smem[RAW_WIH + g * E_F + e] * smem[RAW_BEMB + e];
        smem[OFF_BC + g] = s;
    }

    // ---- W_hh rows for unit jj -> registers (80 VGPRs; fits under the cap) ----
    v2f wi[10], wf[10], wg[10], wo_[10];
    #pragma unroll
    for (int m = 0; m < 10; ++m) {
        wi[m]  = *(const v2f*)(W_hh + (jj          ) * H_F + 2 * m);
        wf[m]  = *(const v2f*)(W_hh + (jj +     H_F) * H_F + 2 * m);
        wg[m]  = *(const v2f*)(W_hh + (jj + 2 * H_F) * H_F + 2 * m);
        wo_[m] = *(const v2f*)(W_hh + (jj + 3 * H_F) * H_F + 2 * m);
    }

    // wave-uniform h pairs (SGPRs via readlane) + per-lane cell state
    v2f hp[10];
    #pragma unroll
    for (int m = 0; m < 10; ++m) hp[m] = (v2f){0.f, 0.f};
    float cc = 0.f;

    const int xgoff = XGOFF(jj);

    #pragma unroll 1
    for (int ch = 0; ch < NCHUNK; ++ch) {
        // ---- P0: stage md chunk (TC rows x 12 floats) ----
        if (lane < TC * 3) {
            int tt = lane / 3, w = lane - tt * 3;
            *(float4*)(smem + OFF_MD + tt * IN_F + w * 4) =
                *(const float4*)(md + ((size_t)(ch * TC + tt) * BATCH + b) * IN_F + w * 4);
        }

        // ---- P2: x_gates for chunk -> swizzled [tt][unit][gate] ----
        for (int idx = lane; idx < TC * G4; idx += 64) {
            int tt = idx / G4, gi = idx - tt * G4;
            int sel = gi / H_F, u = gi - sel * H_F;
            const float4* m4 = (const float4*)(smem + OFF_MD + tt * IN_F);
            const float4* w4 = (const float4*)(smem + OFF_WC + gi * IN_F);
            float4 m0 = m4[0], m1 = m4[1], m2 = m4[2];
            float4 q0 = w4[0], q1 = w4[1], q2 = w4[2];
            float s = smem[OFF_BC + gi];
            s += m0.x*q0.x + m0.y*q0.y + m0.z*q0.z + m0.w*q0.w
               + m1.x*q1.x + m1.y*q1.y + m1.z*q1.z + m1.w*q1.w
               + m2.x*q2.x + m2.y*q2.y + m2.z*q2.z + m2.w*q2.w;
            smem[OFF_XG + tt * 88 + XGOFF(u) + sel] = s;
        }

        // ---- P3: TC recurrent steps ----
        float4 xv = *(const float4*)(smem + OFF_XG + xgoff);
        for (int tt = 0; tt < TC; ++tt) {
            // prefetch next step's 4 gate seeds (independent of h)
            const int tn = (tt + 1 < TC) ? tt + 1 : tt;
            float4 xn = *(const float4*)(smem + OFF_XG + tn * 88 + xgoff);

            // recurrent dots: hp[m] = (h[2m],h[2m+1]) wave-uniform
            v2f aI = {xv.x, 0.f}, aF = {xv.y, 0.f}, aG = {xv.z, 0.f}, aO = {xv.w, 0.f};
            #pragma unroll
            for (int m = 0; m < 10; ++m) {
                aI = pkfma(wi[m],  hp[m], aI);
                aF = pkfma(wf[m],  hp[m], aF);
                aG = pkfma(wg[m],  hp[m], aG);
                aO = pkfma(wo_[m], hp[m], aO);
            }
            float ai = aI.x + aI.y;
            float af = aF.x + aF.y;
            float ag = aG.x + aG.y;
            float ao = aO.x + aO.y;

            float gi_ = fsig(ai);
            float gf  = fsig(af);
            float gt  = ftanh(ag);
            float go  = fsig(ao);
            cc = fmaf(gf, cc, gi_ * gt);
            float hown = go * ftanh(cc);

            // h history for P4 (fire-and-forget; not on the serial chain)
            if (lane < H_F) smem[OFF_HH + tt * H_F + lane] = hown;

            // broadcast h via readlane -> wave-uniform pairs (no LDS round trip)
            int hbits = __float_as_int(hown);
            #pragma unroll
            for (int m = 0; m < 10; ++m) {
                hp[m] = (v2f){ __int_as_float(__builtin_amdgcn_readlane(hbits, 2 * m)),
                               __int_as_float(__builtin_amdgcn_readlane(hbits, 2 * m + 1)) };
            }
            xv = xn;
        }

        // ---- P4: chunk projection + store (48 outputs, one pass) ----
        if (lane < TC * 3) {
            int tt = lane / 3, r = lane - tt * 3;
            const float4* hv4 = (const float4*)(smem + OFF_HH + tt * H_F);
            const float4* wp  = (const float4*)(smem + OFF_WO + r * 24);
            float s = smem[OFF_WO + 72 + r];
            #pragma unroll
            for (int k = 0; k < 5; ++k) {
                float4 hv = hv4[k], wv = wp[k];
                s += hv.x * wv.x + hv.y * wv.y + hv.z * wv.z + hv.w * wv.w;
            }
            out[((size_t)(ch * TC + tt) * BATCH + b) * 3 + r] = s;
        }
    }
}

extern "C" void kernel_launch(void* const* d_in, const int* in_sizes, int n_in,
                              void* d_out, int out_size, void* d_ws, size_t ws_size,
                              hipStream_t stream) {
    const float* md    = (const float*)d_in[0];
    const float* W_emb = (const float*)d_in[1];
    const float* b_emb = (const float*)d_in[2];
    const float* W_ih  = (const float*)d_in[3];
    const float* b_ih  = (const float*)d_in[4];
    const float* W_hh  = (const float*)d_in[5];
    const float* b_hh  = (const float*)d_in[6];
    const float* W_out = (const float*)d_in[7];
    const float* b_out = (const float*)d_in[8];
    float* out = (float*)d_out;

    hipLaunchKernelGGL(lstm_tracker_kernel, dim3(BATCH), dim3(64), 0, stream,
                       md, W_emb, b_emb, W_ih, b_ih, W_hh, b_hh, W_out, b_out, out);
}

// Round 9
// 317.640 us; speedup vs baseline: 1.3691x; 1.3691x over previous
//
#include <hip/hip_runtime.h>

#define T_STEPS 512
#define BATCH   2048
#define IN_F    12
#define E_F     15
#define H_F     20
#define G4      80
#define TC      32
#define NCHUNK  (T_STEPS / TC)

typedef float v2f __attribute__((ext_vector_type(2)));

// LDS float offsets (single wave per block -> no barriers anywhere). 35.2 KB.
#define OFF_MD   0                    // [TC][2][12] md chunk                  = 768
#define OFF_HH   768                  // [TC][2][20] h history                 = 1280
#define OFF_XG   2048                 // [TC][2][88] swizzled x_gates          = 5632
#define OFF_WC   7680                 // 80x12 W_comb                          = 960
#define OFF_BC   8640                 // 80 fused bias                         = 80
#define OFF_WO   8720                 // [3][24] W_out + bias at +72           = 80
#define SMEM_FLOATS 8800              // 35200 bytes

// one-time raw staging aliased over [MD|HH) (first written in chunk 0 P0/P3)
#define RAW_WEMB 0                    // 180
#define RAW_WIH  180                  // 1200
#define RAW_BEMB 1380                 // 15
#define RAW_BIH  1395                 // 80
#define RAW_BHH  1475                 // 80

// xg bank pad: unit u's 4 gate floats at u*4 + ((u>>3)<<2) (16B aligned)
#define XGOFF(u) ((u) * 4 + (((u) >> 3) << 2))

__device__ __forceinline__ float fsig(float x) {
    float e = __builtin_amdgcn_exp2f(x * -1.442695040888963f);
    return __builtin_amdgcn_rcpf(1.0f + e);
}
__device__ __forceinline__ float ftanh(float x) {
    float e = __builtin_amdgcn_exp2f(x * -2.885390081777927f);
    return fmaf(2.0f, __builtin_amdgcn_rcpf(1.0f + e), -1.0f);
}
__device__ __forceinline__ v2f pkfma(v2f a, v2f b, v2f c) {
    return __builtin_elementwise_fma(a, b, c);
}

__global__ void __launch_bounds__(64)
__attribute__((amdgpu_waves_per_eu(1, 1)))
lstm_tracker_kernel(
    const float* __restrict__ md,
    const float* __restrict__ W_emb, const float* __restrict__ b_emb,
    const float* __restrict__ W_ih,  const float* __restrict__ b_ih,
    const float* __restrict__ W_hh,  const float* __restrict__ b_hh,
    const float* __restrict__ W_out, const float* __restrict__ b_out,
    float* __restrict__ out)
{
    __shared__ __align__(16) float smem[SMEM_FLOATS];
    const int lane = threadIdx.x;          // 0..63
    const int bl   = lane >> 5;            // which of the 2 batch elems
    const int j    = lane & 31;            // hidden unit (active if < 20)
    const int jj   = (j < H_F) ? j : 0;    // clamped
    const size_t bbase = (size_t)blockIdx.x * 2;

    // ---- one-time: stage raw weights (single wave; DS in-order) ----
    for (int i = lane; i < E_F * IN_F; i += 64) smem[RAW_WEMB + i] = W_emb[i];
    for (int i = lane; i < G4 * E_F;  i += 64) smem[RAW_WIH  + i] = W_ih[i];
    if (lane < E_F) smem[RAW_BEMB + lane] = b_emb[lane];
    for (int g = lane; g < G4; g += 64) smem[RAW_BIH + g] = b_ih[g];
    for (int g = lane; g < G4; g += 64) smem[RAW_BHH + g] = b_hh[g];
    for (int i = lane; i < 3 * H_F; i += 64) {
        int r = i / H_F, k = i - r * H_F;
        smem[OFF_WO + r * 24 + k] = W_out[i];
    }
    if (lane < 3) smem[OFF_WO + 72 + lane] = b_out[lane];

    // ---- one-time: W_comb = W_ih @ W_emb (80x12); b_comb = W_ih@b_emb + b_ih + b_hh ----
    for (int idx = lane; idx < G4 * IN_F; idx += 64) {
        int g = idx / IN_F, c = idx - g * IN_F;
        float s = 0.f;
        #pragma unroll
        for (int e = 0; e < E_F; ++e)
            s += smem[RAW_WIH + g * E_F + e] * smem[RAW_WEMB + e * IN_F + c];
        smem[OFF_WC + idx] = s;
    }
    for (int g = lane; g < G4; g += 64) {
        float s = smem[RAW_BIH + g] + smem[RAW_BHH + g];
        #pragma unroll
        for (int e = 0; e < E_F; ++e)
            s += smem[RAW_WIH + g * E_F + e] * smem[RAW_BEMB + e];
        smem[OFF_BC + g] = s;
    }

    // ---- W_hh rows for unit jj -> persistent registers (80 VGPRs, fits budget) ----
    v2f whI[10], whF[10], whG[10], whO[10];
    #pragma unroll
    for (int m = 0; m < 10; ++m) {
        whI[m] = *(const v2f*)(W_hh + (jj          ) * H_F + 2 * m);
        whF[m] = *(const v2f*)(W_hh + (jj +     H_F) * H_F + 2 * m);
        whG[m] = *(const v2f*)(W_hh + (jj + 2 * H_F) * H_F + 2 * m);
        whO[m] = *(const v2f*)(W_hh + (jj + 3 * H_F) * H_F + 2 * m);
    }

    v2f h2[10];
    #pragma unroll
    for (int m = 0; m < 10; ++m) h2[m] = (v2f){0.f, 0.f};
    float cc = 0.f;

    const int xgoff = XGOFF(jj);

    #pragma unroll 1
    for (int ch = 0; ch < NCHUNK; ++ch) {
        // ---- P0: stage md chunk (TC rows x 2 seqs x 12 floats, 96B/row coalesced) ----
        for (int idx = lane; idx < TC * 6; idx += 64) {
            int tt = idx / 6, w = idx - tt * 6;
            const float* src = md + ((size_t)(ch * TC + tt) * BATCH + bbase) * IN_F + w * 4;
            *(float4*)(smem + OFF_MD + tt * 24 + w * 4) = *(const float4*)src;
        }

        // ---- P2: x_gates for chunk; lane (bl,jj) computes its unit's 4 gates/tt.
        //      wc rows live in TRANSIENT registers (chunk scope only). ----
        {
            v2f wcI[6], wcF[6], wcG[6], wcO[6];
            #pragma unroll
            for (int k = 0; k < 6; ++k) {
                wcI[k] = *(const v2f*)(smem + OFF_WC + (jj           ) * IN_F + 2 * k);
                wcF[k] = *(const v2f*)(smem + OFF_WC + (jj +     H_F ) * IN_F + 2 * k);
                wcG[k] = *(const v2f*)(smem + OFF_WC + (jj + 2 * H_F ) * IN_F + 2 * k);
                wcO[k] = *(const v2f*)(smem + OFF_WC + (jj + 3 * H_F ) * IN_F + 2 * k);
            }
            const float bcI = smem[OFF_BC + jj];
            const float bcF = smem[OFF_BC + jj + H_F];
            const float bcG = smem[OFF_BC + jj + 2 * H_F];
            const float bcO = smem[OFF_BC + jj + 3 * H_F];

            #pragma unroll 1
            for (int tt = 0; tt < TC; ++tt) {
                const v2f* mv = (const v2f*)(smem + OFF_MD + tt * 24 + bl * IN_F);
                v2f mm0 = mv[0], mm1 = mv[1], mm2 = mv[2];
                v2f mm3 = mv[3], mm4 = mv[4], mm5 = mv[5];
                v2f sI = pkfma(wcI[0], mm0, pkfma(wcI[1], mm1, pkfma(wcI[2], mm2,
                         pkfma(wcI[3], mm3, pkfma(wcI[4], mm4, wcI[5] * mm5)))));
                v2f sF = pkfma(wcF[0], mm0, pkfma(wcF[1], mm1, pkfma(wcF[2], mm2,
                         pkfma(wcF[3], mm3, pkfma(wcF[4], mm4, wcF[5] * mm5)))));
                v2f sG = pkfma(wcG[0], mm0, pkfma(wcG[1], mm1, pkfma(wcG[2], mm2,
                         pkfma(wcG[3], mm3, pkfma(wcG[4], mm4, wcG[5] * mm5)))));
                v2f sO = pkfma(wcO[0], mm0, pkfma(wcO[1], mm1, pkfma(wcO[2], mm2,
                         pkfma(wcO[3], mm3, pkfma(wcO[4], mm4, wcO[5] * mm5)))));
                float4 xgv = { bcI + sI.x + sI.y, bcF + sF.x + sF.y,
                               bcG + sG.x + sG.y, bcO + sO.x + sO.y };
                if (j < H_F)
                    *(float4*)(smem + OFF_XG + tt * 176 + bl * 88 + xgoff) = xgv;
            }
        }

        // ---- P3: TC recurrent steps (serial chain) ----
        float4 xv = *(const float4*)(smem + OFF_XG + bl * 88 + xgoff);
        #pragma unroll 1
        for (int tt = 0; tt < TC; ++tt) {
            const int tn = (tt + 1 < TC) ? tt + 1 : tt;
            float4 xn = *(const float4*)(smem + OFF_XG + tn * 176 + bl * 88 + xgoff);

            v2f aI = {xv.x, 0.f}, aF = {xv.y, 0.f}, aG = {xv.z, 0.f}, aO = {xv.w, 0.f};
            #pragma unroll
            for (int m = 0; m < 10; ++m) {
                aI = pkfma(whI[m], h2[m], aI);
                aF = pkfma(whF[m], h2[m], aF);
                aG = pkfma(whG[m], h2[m], aG);
                aO = pkfma(whO[m], h2[m], aO);
            }
            float ai = aI.x + aI.y;
            float af = aF.x + aF.y;
            float ag = aG.x + aG.y;
            float ao = aO.x + aO.y;

            float gi = fsig(ai);
            float gf = fsig(af);
            float gt = ftanh(ag);
            float go = fsig(ao);
            cc = fmaf(gf, cc, gi * gt);
            float hown = go * ftanh(cc);

            // h -> history slot (feeds P4 AND next-step broadcast read)
            float* hslot = smem + OFF_HH + tt * 40 + bl * 20;
            if (j < H_F) hslot[j] = hown;
            const float4* hr = (const float4*)hslot;
            float4 h0 = hr[0], h1 = hr[1], hx = hr[2], h3 = hr[3], h4 = hr[4];
            h2[0] = (v2f){h0.x, h0.y}; h2[1] = (v2f){h0.z, h0.w};
            h2[2] = (v2f){h1.x, h1.y}; h2[3] = (v2f){h1.z, h1.w};
            h2[4] = (v2f){hx.x, hx.y}; h2[5] = (v2f){hx.z, hx.w};
            h2[6] = (v2f){h3.x, h3.y}; h2[7] = (v2f){h3.z, h3.w};
            h2[8] = (v2f){h4.x, h4.y}; h2[9] = (v2f){h4.z, h4.w};

            xv = xn;
        }

        // ---- P4: chunk projection + store (192 outputs over 64 lanes) ----
        for (int idx = lane; idx < TC * 6; idx += 64) {
            int tt = idx / 6, rem = idx - tt * 6;
            int bb = rem / 3, r = rem - bb * 3;
            const float4* hp = (const float4*)(smem + OFF_HH + tt * 40 + bb * 20);
            const float4* wp = (const float4*)(smem + OFF_WO + r * 24);
            float s = smem[OFF_WO + 72 + r];
            #pragma unroll
            for (int k = 0; k < 5; ++k) {
                float4 hv = hp[k], wv = wp[k];
                s += hv.x * wv.x + hv.y * wv.y + hv.z * wv.z + hv.w * wv.w;
            }
            out[((size_t)(ch * TC + tt) * BATCH + bbase + bb) * 3 + r] = s;
        }
    }
}

extern "C" void kernel_launch(void* const* d_in, const int* in_sizes, int n_in,
                              void* d_out, int out_size, void* d_ws, size_t ws_size,
                              hipStream_t stream) {
    const float* md    = (const float*)d_in[0];
    const float* W_emb = (const float*)d_in[1];
    const float* b_emb = (const float*)d_in[2];
    const float* W_ih  = (const float*)d_in[3];
    const float* b_ih  = (const float*)d_in[4];
    const float* W_hh  = (const float*)d_in[5];
    const float* b_hh  = (const float*)d_in[6];
    const float* W_out = (const float*)d_in[7];
    const float* b_out = (const float*)d_in[8];
    float* out = (float*)d_out;

    hipLaunchKernelGGL(lstm_tracker_kernel, dim3(BATCH / 2), dim3(64), 0, stream,
                       md, W_emb, b_emb, W_ih, b_ih, W_hh, b_hh, W_out, b_out, out);
}